// Round 2
// 71.021 us; speedup vs baseline: 1.0218x; 1.0218x over previous
//
#include <hip/hip_runtime.h>

// RLSE forward — fused single-launch formulation.
//
// Structural fact #1: in the reference's own fp arithmetic, S always has
// exactly TWO distinct values: S = ov*1*1^T + (dv-ov)*I, so
// S@a = dv*a + ov*(suma - a). The 256x256 scan state collapses to
// {dv, ov, theta[256]} -> one wave, no barriers needed for the scan itself.
//
// Structural fact #2: gamma=1000 divides dv, ov, theta every step, so the
// state underflows to EXACTLY 0 by step ~17; (0,0,0) is an exact fixed
// point. We scan faithfully and exit once the state is exactly zero
// (checked via ballot, never assumed).
//
// Launch fusion: ONE kernel. Every block redundantly runs the ~18-step
// scan on its wave 0 (rows 0..18 of x/f are broadcast via L2 across
// blocks; ~1.2MB HBM total over 8 XCDs), shares theta through LDS, then
// each wave emits its output row. When the scan verifiably ends at
// theta==0, the output is exactly 0 (inputs finite), written coalesced
// with no x read. Honest per-row dot-product fallback kept for theta!=0.

#define NN 256  // n_vars + 1

__global__ __launch_bounds__(256) void rlse_fused_kernel(
    const float* __restrict__ x, const float* __restrict__ f,
    const float* __restrict__ y, float* __restrict__ out, int rows)
{
    __shared__ float s_theta[NN];
    __shared__ int   s_thzero;

    const int lane = threadIdx.x & 63;
    const int wave = threadIdx.x >> 6;

    if (wave == 0) {
        const int l = lane;  // owns theta[4l..4l+3]
        const float4* x4 = (const float4*)x;
        const float4* f4 = (const float4*)f;

        float th0 = 0.0f, th1 = 0.0f, th2 = 0.0f, th3 = 0.0f;
        float dv = 1.0f;  // S diagonal value (uniform)
        float ov = 0.0f;  // S off-diagonal value (uniform)

        // depth-2 rotating prefetch: cur (this iter), nxt (next iter)
        float4 cx = x4[l], cf = f4[l];
        float  cy = y[0];
        float4 nx = cx, nf = cf;
        float  ny = 0.0f;
        if (rows > 1) { nx = x4[64 + l]; nf = f4[64 + l]; ny = y[1]; }

        for (int k = 0; k < rows; ++k) {
            // a = x*f for this row (per-lane 4 elements)
            const float a0 = cx.x * cf.x, a1 = cx.y * cf.y;
            const float a2 = cx.z * cf.z, a3 = cx.w * cf.w;

            // issue load for row k+2 now; 2 iterations (~600cy) to cover it
            float4 fx = nx, ff = nf; float fy = 0.0f;
            if (k + 2 < rows) {
                fx = x4[(size_t)(k + 2) * 64 + l];
                ff = f4[(size_t)(k + 2) * 64 + l];
                fy = y[k + 2];
            }

            // three batched butterfly reductions: suma, s2=a.a, ta=a.theta
            float ps = a0 + a1 + a2 + a3;
            float p2 = a0 * a0 + a1 * a1 + a2 * a2 + a3 * a3;
            float pt = a0 * th0 + a1 * th1 + a2 * th2 + a3 * th3;
#pragma unroll
            for (int off = 32; off > 0; off >>= 1) {
                ps += __shfl_xor(ps, off, 64);
                p2 += __shfl_xor(p2, off, 64);
                pt += __shfl_xor(pt, off, 64);
            }
            const float suma = ps, s2 = p2;
            const float e = cy - pt;                 // e = b - a.theta (OLD theta)

            const float x2 = 1.0f + dv * s2;
            const float c  = (dv * dv) * s2 / x2;    // d_i*d_j*s2/x2 (all entries)

            // z = S@a = dv*a + ov*(suma - a); theta' = (theta + z*e)*1e-3
            const float z0 = dv * a0 + ov * (suma - a0);
            const float z1 = dv * a1 + ov * (suma - a1);
            const float z2 = dv * a2 + ov * (suma - a2);
            const float z3 = dv * a3 + ov * (suma - a3);
            th0 = (th0 + z0 * e) * 0.001f;
            th1 = (th1 + z1 * e) * 0.001f;
            th2 = (th2 + z2 * e) * 0.001f;
            th3 = (th3 + z3 * e) * 0.001f;

            dv = (dv - c) * 0.001f;
            ov = (ov - c) * 0.001f;

            cx = nx; cf = nf; cy = ny;
            nx = fx; nf = ff; ny = fy;

            // early exit: state exactly zero => provable fixed point
            if (k >= 13) {
                const bool nzs = (dv != 0.0f) | (ov != 0.0f) |
                                 (th0 != 0.0f) | (th1 != 0.0f) |
                                 (th2 != 0.0f) | (th3 != 0.0f);
                if (__ballot(nzs) == 0ULL) break;
            }
        }

        float4 t4; t4.x = th0; t4.y = th1; t4.z = th2; t4.w = th3;
        ((float4*)s_theta)[l] = t4;
        const bool nzf = (th0 != 0.0f) | (th1 != 0.0f) |
                         (th2 != 0.0f) | (th3 != 0.0f);
        const unsigned long long m = __ballot(nzf);
        if (l == 0) s_thzero = (m == 0ULL) ? 1 : 0;
    }
    __syncthreads();

    if (s_thzero) {
        // theta is exactly zero -> out[r] = dot(x[r], 0) = 0 exactly
        // (inputs finite). Coalesced zero-fill, no x read.
        const int gid = blockIdx.x * blockDim.x + threadIdx.x;
        const int stride = gridDim.x * blockDim.x;
        for (int i = gid; i < rows; i += stride) out[i] = 0.0f;
        return;
    }

    // honest path: out[r] = dot(x[r, :], theta) — one wave per row
    const float4 tv = ((const float4*)s_theta)[lane];
    const int wpg = gridDim.x * 4;  // waves in grid
    for (int r = blockIdx.x * 4 + wave; r < rows; r += wpg) {
        const float4 xv = ((const float4*)(x + (size_t)r * NN))[lane];
        float s = xv.x * tv.x + xv.y * tv.y + xv.z * tv.z + xv.w * tv.w;
#pragma unroll
        for (int off = 32; off > 0; off >>= 1) s += __shfl_xor(s, off, 64);
        if (lane == 0) out[r] = s;
    }
}

extern "C" void kernel_launch(void* const* d_in, const int* in_sizes, int n_in,
                              void* d_out, int out_size, void* d_ws, size_t ws_size,
                              hipStream_t stream)
{
    const float* x = (const float*)d_in[0];   // (B, R, N) fp32
    const float* f = (const float*)d_in[1];   // (B, R, N) fp32
    const float* y = (const float*)d_in[2];   // (B, R, 1) fp32
    float* out = (float*)d_out;               // (B, R, 1) fp32
    const int rows = in_sizes[2];             // B*R sequential steps

    int blocks = (rows + 3) / 4;              // one wave per output row
    if (blocks < 1) blocks = 1;
    rlse_fused_kernel<<<blocks, 256, 0, stream>>>(x, f, y, out, rows);
}